// Round 5
// baseline (158.649 us; speedup 1.0000x reference)
//
#include <hip/hip_runtime.h>
#include <cstdint>
#include <cstddef>

typedef unsigned short u16;
typedef __attribute__((ext_vector_type(8))) short bf16x8;
typedef __attribute__((ext_vector_type(8))) unsigned short u16x8;
typedef __attribute__((ext_vector_type(4))) float f32x4;

// ---------- helpers ----------
__device__ __forceinline__ u16 f2b(float f) {
    union { float f; uint32_t u; } v; v.f = f;
    uint32_t u = v.u;
    uint32_t r = (u + 0x7FFFu + ((u >> 16) & 1u)) >> 16;
    return (u16)r;
}
__device__ __forceinline__ float b2f(u16 b) {
    union { uint32_t u; float f; } v; v.u = ((uint32_t)b) << 16;
    return v.f;
}
__device__ __forceinline__ void gload_lds16(const void* g, void* l) {
    __builtin_amdgcn_global_load_lds(
        (const __attribute__((address_space(1))) void*)g,
        (__attribute__((address_space(3))) void*)l,
        16, 0, 0);
}

// ---------- prep building blocks (256-thread blocks) ----------
__device__ __forceinline__ void cvt_block(const float* __restrict__ in,
                                          u16* __restrict__ outp, int bb, int tid) {
    size_t base = (size_t)bb * 2048 + (size_t)tid * 8;
    const float4* p = (const float4*)(in + base);
    float4 a = p[0], c = p[1];
    u16x8 o;
    o[0] = f2b(a.x); o[1] = f2b(a.y); o[2] = f2b(a.z); o[3] = f2b(a.w);
    o[4] = f2b(c.x); o[5] = f2b(c.y); o[6] = f2b(c.z); o[7] = f2b(c.w);
    *(u16x8*)(outp + base) = o;
}

__device__ __forceinline__ void transpose_block(const float* __restrict__ in,
                                                u16* __restrict__ outp,
                                                int K, int N, int t, int tid,
                                                float (*tile)[33]) {
    const int ntx = N >> 5;
    const int n0 = (t % ntx) * 32, k0 = (t / ntx) * 32;
    const int tx = tid & 31, ty = tid >> 5;
#pragma unroll
    for (int r = ty; r < 32; r += 8)
        tile[r][tx] = in[(size_t)(k0 + r) * N + n0 + tx];
    __syncthreads();
#pragma unroll
    for (int r = ty; r < 32; r += 8)
        outp[(size_t)(n0 + r) * K + k0 + tx] = f2b(tile[tx][r]);
}

// ---------- prep1 (256 thr): all converts/transposes + b34 ----------
// [0,2048)       feat [4096,1024] f32->bf16
// [2048,3072)    W3   [2048,1024] f32->bf16
// [3072,5120)    W1   [1024,2048] -> W1T [2048,1024]
// [5120,5632)    Wh   [1024,512]  -> WhT [512,1024]
// [5632,7680)    w    [512,4096]  -> wTb [4096,512]
// [7680,11776)   W2   [2048,2048] -> W2T
// [11776,11778)  b34[j] = b3 . Wh[:,j] + bh[j]
__global__ __launch_bounds__(256) void prep1_kernel(
    const float* __restrict__ feat, u16* __restrict__ featB,
    const float* __restrict__ W1, u16* __restrict__ W1T,
    const float* __restrict__ W2, u16* __restrict__ W2T,
    const float* __restrict__ W3, u16* __restrict__ W3c,
    const float* __restrict__ Wh, u16* __restrict__ WhT,
    const float* __restrict__ w, u16* __restrict__ wTb,
    const float* __restrict__ b3, const float* __restrict__ bh,
    float* __restrict__ b34) {
    __shared__ float tile[32][33];
    const int b = blockIdx.x, tid = threadIdx.x;
    if (b < 2048)  { cvt_block(feat, featB, b, tid); return; }
    if (b < 3072)  { cvt_block(W3, W3c, b - 2048, tid); return; }
    if (b < 5120)  { transpose_block(W1, W1T, 1024, 2048, b - 3072, tid, tile); return; }
    if (b < 5632)  { transpose_block(Wh, WhT, 1024, 512, b - 5120, tid, tile); return; }
    if (b < 7680)  { transpose_block(w, wTb, 512, 4096, b - 5632, tid, tile); return; }
    if (b < 11776) { transpose_block(W2, W2T, 2048, 2048, b - 7680, tid, tile); return; }
    {
        int j = (b - 11776) * 256 + tid;  // [0,512)
        float s = bh[j];
        for (int k = 0; k < 1024; ++k)
            s += b3[k] * Wh[(size_t)k * 512 + j];
        b34[j] = s;
    }
}

// =====================================================================
// Pipelined GEMM: C[M,N] = act(A[M,K] @ BT[N,K]^T + bias)
// BM=128, BN=256, BK=64. 512 threads = 8 waves (2m x 4n), per-wave 64x64.
// Double-buffered LDS (A 16KB + B 32KB per buffer = 96KB total).
// 2 phases per K-tile; counted vmcnt(4) (loads stay in flight across
// barriers); T2 XOR swizzle (byte ^= (row&7)<<4) on LDS; T5 setprio.
// =====================================================================

// stage one 16KB unit: 128 rows x 64 bf16 cols from g[(r)*ldg + swz-col]
// LDS dest is linear (wave-uniform base + lane*16); swizzle is applied by
// permuting the SOURCE chunk within each 128B row: ch = (c&7)^(r&7).
__device__ __forceinline__ void stage_unit(const u16* __restrict__ g, int ldg,
                                           u16* lds, int tid) {
#pragma unroll
    for (int j = 0; j < 2; ++j) {
        int c = tid + j * 512;
        int r = c >> 3;
        int ch = (c & 7) ^ (r & 7);
        gload_lds16(g + (size_t)r * ldg + ch * 8, (char*)lds + c * 16);
    }
}

// read one MFMA fragment from swizzled LDS: logical (row, kk, lg)
__device__ __forceinline__ bf16x8 lds_frag(const u16* s, int row, int kk, int lg) {
    int byte = (row << 7) + (kk << 6) + (lg << 4);
    byte ^= (row & 7) << 4;
    return *(const bf16x8*)((const char*)s + byte);
}

template <int RELU, int HB>
__device__ __forceinline__ void gemm8_body(
    const u16* __restrict__ A, const u16* __restrict__ BT,
    const float* __restrict__ bias, u16* __restrict__ C,
    int N, int K, int bx, int by, u16* sA, u16* sB) {
    const int tid = threadIdx.x;
    const int lane = tid & 63;
    const int wv = tid >> 6;
    const int wm = wv >> 2, wn = wv & 3;     // 2 x 4 waves
    const int lr = lane & 15, lg = lane >> 4;
    const int rowBase = by * 128;
    const int colBase = bx * 256;
    const int nt = K >> 6;

    const u16* Ag = A + (size_t)rowBase * K;
    const u16* Bg = BT + (size_t)colBase * K;

    f32x4 acc[4][4] = {};

    // prologue: stage tile 0 (A, B0, B1 = 6 loads/thread) into buf0
    stage_unit(Ag, K, sA, tid);
    stage_unit(Bg, K, sB, tid);
    stage_unit(Bg + (size_t)128 * K, K, sB + 8192, tid);

    for (int t = 0; t < nt; ++t) {
        const int cur = t & 1, nxt = cur ^ 1;
        const u16* sAc = sA + cur * 8192;
        const u16* sBc = sB + cur * 16384;
        const int kb2 = (t + 1) << 6;

        // ---- phase 0 ----
        if (t + 1 < nt) {
            stage_unit(Ag + kb2, K, sA + nxt * 8192, tid);
            stage_unit(Bg + kb2, K, sB + nxt * 16384, tid);
            // oldest outstanding = tile t's remaining loads; the 4 just
            // issued are allowed to stay in flight.
            asm volatile("s_waitcnt vmcnt(4)" ::: "memory");
        } else {
            asm volatile("s_waitcnt vmcnt(0)" ::: "memory");
        }
        __builtin_amdgcn_sched_barrier(0);
        __builtin_amdgcn_s_barrier();

        bf16x8 bfr[4][2], af[2][2];
#pragma unroll
        for (int n = 0; n < 4; ++n)
#pragma unroll
            for (int kk = 0; kk < 2; ++kk)
                bfr[n][kk] = lds_frag(sBc, wn * 64 + n * 16 + lr, kk, lg);
#pragma unroll
        for (int mi = 0; mi < 2; ++mi)
#pragma unroll
            for (int kk = 0; kk < 2; ++kk)
                af[mi][kk] = lds_frag(sAc, wm * 64 + mi * 16 + lr, kk, lg);

        __builtin_amdgcn_s_setprio(1);
#pragma unroll
        for (int kk = 0; kk < 2; ++kk)
#pragma unroll
            for (int mi = 0; mi < 2; ++mi)
#pragma unroll
                for (int n = 0; n < 4; ++n)
                    acc[mi][n] = __builtin_amdgcn_mfma_f32_16x16x32_bf16(
                        af[mi][kk], bfr[n][kk], acc[mi][n], 0, 0, 0);
        __builtin_amdgcn_s_setprio(0);
        __builtin_amdgcn_s_barrier();

        // ---- phase 1 ----
        bf16x8 af2[2][2];
#pragma unroll
        for (int mi = 0; mi < 2; ++mi)
#pragma unroll
            for (int kk = 0; kk < 2; ++kk)
                af2[mi][kk] = lds_frag(sAc, wm * 64 + (2 + mi) * 16 + lr, kk, lg);
        if (t + 1 < nt)
            stage_unit(Bg + (size_t)128 * K + kb2, K, sB + nxt * 16384 + 8192, tid);
        __builtin_amdgcn_s_barrier();

        __builtin_amdgcn_s_setprio(1);
#pragma unroll
        for (int kk = 0; kk < 2; ++kk)
#pragma unroll
            for (int mi = 0; mi < 2; ++mi)
#pragma unroll
                for (int n = 0; n < 4; ++n)
                    acc[2 + mi][n] = __builtin_amdgcn_mfma_f32_16x16x32_bf16(
                        af2[mi][kk], bfr[n][kk], acc[2 + mi][n], 0, 0, 0);
        __builtin_amdgcn_s_setprio(0);
        __builtin_amdgcn_s_barrier();
    }

    // epilogue
#pragma unroll
    for (int n = 0; n < 4; ++n) {
        int col = colBase + wn * 64 + n * 16 + lr;
        float bv = HB ? bias[col] : 0.f;
#pragma unroll
        for (int m = 0; m < 4; ++m) {
            int row0 = rowBase + wm * 64 + m * 16 + lg * 4;
#pragma unroll
            for (int i = 0; i < 4; ++i) {
                float v = acc[m][n][i] + bv;
                if (RELU) v = v > 0.f ? v : 0.f;
                C[(size_t)(row0 + i) * N + col] = f2b(v);
            }
        }
    }
}

// ---------- groupedA (512 thr, 296 blocks) ----------
// [0,256)    GEMM1: h1 = relu(featB @ W1T^T + b1)  M=4096 N=2048 K=1024
// [256,288)  W34 = W3c @ WhT^T                     M=2048 N=512  K=1024
// [288,296)  c[n] = b34 . w[:,n]
__global__ __launch_bounds__(512, 2) void groupedA_kernel(
    const u16* __restrict__ featB, const u16* __restrict__ W1T,
    const float* __restrict__ b1, u16* __restrict__ h1,
    const u16* __restrict__ W3c, const u16* __restrict__ WhT, u16* __restrict__ W34,
    const float* __restrict__ b34, const float* __restrict__ w, float* __restrict__ c) {
    __shared__ __align__(16) u16 sA[2 * 8192];
    __shared__ __align__(16) u16 sB[2 * 16384];
    const int b = blockIdx.x;
    if (b < 256) {
        gemm8_body<1, 1>(featB, W1T, b1, h1, 2048, 1024, b & 7, b >> 3, sA, sB);
    } else if (b < 288) {
        int g = b - 256;
        gemm8_body<0, 0>(W3c, WhT, nullptr, W34, 512, 1024, g & 1, g >> 1, sA, sB);
    } else {
        int n = (b - 288) * 512 + threadIdx.x;  // [0,4096)
        float s = 0.f;
        for (int j = 0; j < 512; ++j)
            s += b34[j] * w[(size_t)j * 4096 + n];
        c[n] = s;
    }
}

// ---------- groupedB (512 thr, 512 blocks) ----------
// [0,256)    GEMM2: h2 = relu(h1 @ W2T^T + b2)  M=4096 N=2048 K=2048
// [256,512)  UT = wTb @ W34^T                   M=4096 N=2048 K=512
__global__ __launch_bounds__(512, 2) void groupedB_kernel(
    const u16* __restrict__ h1, const u16* __restrict__ W2T,
    const float* __restrict__ b2, u16* __restrict__ h2,
    const u16* __restrict__ wTb, const u16* __restrict__ W34, u16* __restrict__ UT) {
    __shared__ __align__(16) u16 sA[2 * 8192];
    __shared__ __align__(16) u16 sB[2 * 16384];
    const int b = blockIdx.x;
    if (b < 256) {
        gemm8_body<1, 1>(h1, W2T, b2, h2, 2048, 2048, b & 7, b >> 3, sA, sB);
    } else {
        int g = b - 256;
        gemm8_body<0, 0>(wTb, W34, nullptr, UT, 2048, 512, g & 7, g >> 3, sA, sB);
    }
}

// ---------- final dot: out[n] = c[n] + sum_k h2[n,k]*UT[n,k] ----------
__global__ __launch_bounds__(256) void dot_kernel(
    const u16* __restrict__ h2, const u16* __restrict__ UT,
    const float* __restrict__ c, float* __restrict__ out) {
    const int n = blockIdx.x * 4 + (threadIdx.x >> 6);
    const int lane = threadIdx.x & 63;
    const u16* hrow = h2 + (size_t)n * 2048;
    const u16* urow = UT + (size_t)n * 2048;
    float s = 0.f;
#pragma unroll
    for (int chk = 0; chk < 4; ++chk) {
        int o = chk * 512 + lane * 8;
        u16x8 hv = *(const u16x8*)(hrow + o);
        u16x8 uv = *(const u16x8*)(urow + o);
#pragma unroll
        for (int t = 0; t < 8; ++t) s += b2f(hv[t]) * b2f(uv[t]);
    }
#pragma unroll
    for (int off = 32; off; off >>= 1) s += __shfl_xor(s, off);
    if (lane == 0) out[n] = c[n] + s;
}

// ---------- launch ----------
extern "C" void kernel_launch(void* const* d_in, const int* in_sizes, int n_in,
                              void* d_out, int out_size, void* d_ws, size_t ws_size,
                              hipStream_t stream) {
    const float* features = (const float*)d_in[0];
    const float* W1 = (const float*)d_in[1];
    const float* b1 = (const float*)d_in[2];
    const float* W2 = (const float*)d_in[3];
    const float* b2 = (const float*)d_in[4];
    const float* W3 = (const float*)d_in[5];
    const float* b3 = (const float*)d_in[6];
    const float* Wh = (const float*)d_in[7];
    const float* bh = (const float*)d_in[8];
    const float* w  = (const float*)d_in[9];
    float* out = (float*)d_out;

    size_t off = 0;
    auto alloc = [&](size_t bytes) {
        void* p = (char*)d_ws + off;
        off += (bytes + 255) & ~(size_t)255;
        return p;
    };
    // featB/W1T/W3c are dead after groupedA; UT (16MB) aliases them.
    u16* featB = (u16*)alloc((size_t)4096 * 1024 * 2);   // 8MB
    u16* W1T   = (u16*)alloc((size_t)2048 * 1024 * 2);   // 4MB
    u16* W3c   = (u16*)alloc((size_t)2048 * 1024 * 2);   // 4MB
    u16* UT    = featB;                                  // [4096,2048] bf16
    u16* WhT   = (u16*)alloc((size_t)512 * 1024 * 2);    // 1MB
    u16* W2T   = (u16*)alloc((size_t)2048 * 2048 * 2);   // 8MB
    u16* wTb   = (u16*)alloc((size_t)4096 * 512 * 2);    // 4MB
    u16* W34   = (u16*)alloc((size_t)2048 * 512 * 2);    // 2MB
    float* b34 = (float*)alloc((size_t)512 * 4);
    float* c   = (float*)alloc((size_t)4096 * 4);
    u16* h1    = (u16*)alloc((size_t)4096 * 2048 * 2);   // 16MB
    u16* h2    = (u16*)alloc((size_t)4096 * 2048 * 2);   // 16MB

    // 1. prep: all converts/transposes (incl. W2T) + b34
    prep1_kernel<<<11778, 256, 0, stream>>>(features, featB, W1, W1T, W2, W2T,
                                            W3, W3c, Wh, WhT, w, wTb, b3, bh, b34);

    // 2. groupedA: GEMM1 || W34 || c
    groupedA_kernel<<<296, 512, 0, stream>>>(featB, W1T, b1, h1,
                                             W3c, WhT, W34, b34, w, c);

    // 3. groupedB: GEMM2 || UT
    groupedB_kernel<<<512, 512, 0, stream>>>(h1, W2T, b2, h2, wTb, W34, UT);

    // 4. final row-dot
    dot_kernel<<<1024, 256, 0, stream>>>(h2, UT, c, out);
}

// Round 6
// 153.479 us; speedup vs baseline: 1.0337x; 1.0337x over previous
//
#include <hip/hip_runtime.h>
#include <cstdint>
#include <cstddef>

typedef unsigned short u16;
typedef __attribute__((ext_vector_type(8))) short bf16x8;
typedef __attribute__((ext_vector_type(8))) unsigned short u16x8;
typedef __attribute__((ext_vector_type(4))) unsigned short u16x4;
typedef __attribute__((ext_vector_type(4))) float f32x4;

// ---------- helpers ----------
__device__ __forceinline__ u16 f2b(float f) {
    union { float f; uint32_t u; } v; v.f = f;
    uint32_t u = v.u;
    uint32_t r = (u + 0x7FFFu + ((u >> 16) & 1u)) >> 16;
    return (u16)r;
}
__device__ __forceinline__ float b2f(u16 b) {
    union { uint32_t u; float f; } v; v.u = ((uint32_t)b) << 16;
    return v.f;
}
__device__ __forceinline__ void gload_lds16(const void* g, void* l) {
    __builtin_amdgcn_global_load_lds(
        (const __attribute__((address_space(1))) void*)g,
        (__attribute__((address_space(3))) void*)l,
        16, 0, 0);
}

// ---------- prep building blocks ----------
// straight f32 -> bf16, 2048 elems per 256-thr block
__device__ __forceinline__ void cvt_block(const float* __restrict__ in,
                                          u16* __restrict__ outp, int bb, int tid) {
    size_t base = (size_t)bb * 2048 + (size_t)tid * 8;
    const float4* p = (const float4*)(in + base);
    float4 a = p[0], c = p[1];
    u16x8 o;
    o[0] = f2b(a.x); o[1] = f2b(a.y); o[2] = f2b(a.z); o[3] = f2b(a.w);
    o[4] = f2b(c.x); o[5] = f2b(c.y); o[6] = f2b(c.z); o[7] = f2b(c.w);
    *(u16x8*)(outp + base) = o;
}

// 64x64 f32 tile transpose -> bf16, 256 threads
__device__ __forceinline__ void transpose64_256(const float* __restrict__ in,
                                                u16* __restrict__ outp,
                                                int K, int N, int t, int tid,
                                                float (*tile)[65]) {
    const int ntx = N >> 6;
    const int n0 = (t % ntx) * 64, k0 = (t / ntx) * 64;
    const int r0 = tid >> 4, c4 = tid & 15;
#pragma unroll
    for (int j = 0; j < 4; ++j) {
        int r = r0 + j * 16;
        float4 v = *(const float4*)(in + (size_t)(k0 + r) * N + n0 + c4 * 4);
        tile[r][c4 * 4 + 0] = v.x; tile[r][c4 * 4 + 1] = v.y;
        tile[r][c4 * 4 + 2] = v.z; tile[r][c4 * 4 + 3] = v.w;
    }
    __syncthreads();
    const int rr = tid >> 2;
#pragma unroll
    for (int j = 0; j < 4; ++j) {
        int ch = (tid & 3) + j * 4;
        u16x4 o;
        o[0] = f2b(tile[ch * 4 + 0][rr]); o[1] = f2b(tile[ch * 4 + 1][rr]);
        o[2] = f2b(tile[ch * 4 + 2][rr]); o[3] = f2b(tile[ch * 4 + 3][rr]);
        *(u16x4*)(outp + (size_t)(n0 + rr) * K + k0 + ch * 4) = o;
    }
    __syncthreads();
}

// 64x64 f32 tile transpose -> bf16, 512 threads
__device__ __forceinline__ void transpose64_512(const float* __restrict__ in,
                                                u16* __restrict__ outp,
                                                int K, int N, int t, int tid,
                                                float (*tile)[65]) {
    const int ntx = N >> 6;
    const int n0 = (t % ntx) * 64, k0 = (t / ntx) * 64;
    const int r0 = tid >> 4, c4 = tid & 15;
#pragma unroll
    for (int j = 0; j < 2; ++j) {
        int r = r0 + j * 32;
        float4 v = *(const float4*)(in + (size_t)(k0 + r) * N + n0 + c4 * 4);
        tile[r][c4 * 4 + 0] = v.x; tile[r][c4 * 4 + 1] = v.y;
        tile[r][c4 * 4 + 2] = v.z; tile[r][c4 * 4 + 3] = v.w;
    }
    __syncthreads();
    const int rr = tid >> 3;
#pragma unroll
    for (int j = 0; j < 2; ++j) {
        int ch = (tid & 7) + j * 8;
        u16x4 o;
        o[0] = f2b(tile[ch * 4 + 0][rr]); o[1] = f2b(tile[ch * 4 + 1][rr]);
        o[2] = f2b(tile[ch * 4 + 2][rr]); o[3] = f2b(tile[ch * 4 + 3][rr]);
        *(u16x4*)(outp + (size_t)(n0 + rr) * K + k0 + ch * 4) = o;
    }
    __syncthreads();
}

// ---------- prep1 (256 thr, 3714 blocks) ----------
// [0,2048)     feat [4096,1024] f32->bf16
// [2048,3072)  W3   [2048,1024] f32->bf16
// [3072,3584)  W1   [1024,2048] -> W1T (512 64x64 tiles)
// [3584,3712)  Wh   [1024,512]  -> WhT (128 tiles)
// [3712,3714)  b34[j] = b3 . Wh[:,j] + bh[j]
__global__ __launch_bounds__(256) void prep1_kernel(
    const float* __restrict__ feat, u16* __restrict__ featB,
    const float* __restrict__ W1, u16* __restrict__ W1T,
    const float* __restrict__ W3, u16* __restrict__ W3c,
    const float* __restrict__ Wh, u16* __restrict__ WhT,
    const float* __restrict__ b3, const float* __restrict__ bh,
    float* __restrict__ b34) {
    __shared__ float tile[64][65];
    const int b = blockIdx.x, tid = threadIdx.x;
    if (b < 2048) { cvt_block(feat, featB, b, tid); return; }
    if (b < 3072) { cvt_block(W3, W3c, b - 2048, tid); return; }
    if (b < 3584) { transpose64_256(W1, W1T, 1024, 2048, b - 3072, tid, tile); return; }
    if (b < 3712) { transpose64_256(Wh, WhT, 1024, 512, b - 3584, tid, tile); return; }
    {
        int j = (b - 3712) * 256 + tid;  // [0,512)
        float s = bh[j];
        for (int k = 0; k < 1024; ++k)
            s += b3[k] * Wh[(size_t)k * 512 + j];
        b34[j] = s;
    }
}

// =====================================================================
// Triple-buffered pipelined GEMM: C[M,N] = act(A[M,K] @ BT[N,K]^T + bias)
// BM=128, BN=256, BK=64. 512 threads = 8 waves (2m x 4n), per-wave 64x64.
// LDS: 3 buffers x (A 16KB + B 32KB) = 144KB. Tile t+2 staged while
// computing t -> issue-to-gate distance = 2 tiles >> HBM latency.
// Uniform gate vmcnt(6) (2 tiles = 12 loads stay in flight), vmcnt(0)
// only on the final tile. T2 XOR swizzle; T5 setprio.
// =====================================================================

// stage one 16KB unit: 128 rows x 64 bf16 cols; source chunk pre-swizzled
// (ch = (c&7)^(r&7)) so linear LDS dest + swizzled read agree.
__device__ __forceinline__ void stage_unit(const u16* __restrict__ g, int ldg,
                                           u16* lds, int tid) {
#pragma unroll
    for (int j = 0; j < 2; ++j) {
        int c = tid + j * 512;
        int r = c >> 3;
        int ch = (c & 7) ^ (r & 7);
        gload_lds16(g + (size_t)r * ldg + ch * 8, (char*)lds + c * 16);
    }
}

__device__ __forceinline__ bf16x8 lds_frag(const u16* s, int row, int kk, int lg) {
    int byte = (row << 7) + (kk << 6) + (lg << 4);
    byte ^= (row & 7) << 4;
    return *(const bf16x8*)((const char*)s + byte);
}

template <int RELU, int HB>
__device__ __forceinline__ void gemm8_body(
    const u16* __restrict__ A, const u16* __restrict__ BT,
    const float* __restrict__ bias, u16* __restrict__ C,
    int N, int K, int bx, int by, u16* sA, u16* sB) {
    const int tid = threadIdx.x;
    const int lane = tid & 63;
    const int wv = tid >> 6;
    const int wm = wv >> 2, wn = wv & 3;     // 2 x 4 waves
    const int lr = lane & 15, lg = lane >> 4;
    const int rowBase = by * 128;
    const int colBase = bx * 256;
    const int nt = K >> 6;

    const u16* Ag = A + (size_t)rowBase * K;
    const u16* Bg = BT + (size_t)colBase * K;

    f32x4 acc[4][4] = {};

    // prologue: stage tiles 0 and 1 (6 loads/thread each)
    stage_unit(Ag, K, sA, tid);
    stage_unit(Bg, K, sB, tid);
    stage_unit(Bg + (size_t)128 * K, K, sB + 8192, tid);
    stage_unit(Ag + 64, K, sA + 8192, tid);
    stage_unit(Bg + 64, K, sB + 16384, tid);
    stage_unit(Bg + (size_t)128 * K + 64, K, sB + 16384 + 8192, tid);

    for (int t = 0; t < nt; ++t) {
        const int cb = t % 3;
        const int nb = (t + 2) % 3;
        const u16* sAc = sA + cb * 8192;
        const u16* sBc = sB + cb * 16384;
        const int kb2 = (t + 2) << 6;

        // gate: drain tile t's 6 loads; keep t+1 (and t+2 once issued) flying
        if (t + 1 < nt) {
            asm volatile("s_waitcnt vmcnt(6)" ::: "memory");
        } else {
            asm volatile("s_waitcnt vmcnt(0)" ::: "memory");
        }
        __builtin_amdgcn_sched_barrier(0);

        // stage tile t+2 (A + B0) into the buffer freed by tile t-1
        if (t + 2 < nt) {
            stage_unit(Ag + kb2, K, sA + nb * 8192, tid);
            stage_unit(Bg + kb2, K, sB + nb * 16384, tid);
        }
        __builtin_amdgcn_s_barrier();

        // ---- phase 0: mi 0-1 ----
        bf16x8 bfr[4][2], af[2][2];
#pragma unroll
        for (int n = 0; n < 4; ++n)
#pragma unroll
            for (int kk = 0; kk < 2; ++kk)
                bfr[n][kk] = lds_frag(sBc, wn * 64 + n * 16 + lr, kk, lg);
#pragma unroll
        for (int mi = 0; mi < 2; ++mi)
#pragma unroll
            for (int kk = 0; kk < 2; ++kk)
                af[mi][kk] = lds_frag(sAc, wm * 64 + mi * 16 + lr, kk, lg);

        __builtin_amdgcn_s_setprio(1);
#pragma unroll
        for (int kk = 0; kk < 2; ++kk)
#pragma unroll
            for (int mi = 0; mi < 2; ++mi)
#pragma unroll
                for (int n = 0; n < 4; ++n)
                    acc[mi][n] = __builtin_amdgcn_mfma_f32_16x16x32_bf16(
                        af[mi][kk], bfr[n][kk], acc[mi][n], 0, 0, 0);
        __builtin_amdgcn_s_setprio(0);
        __builtin_amdgcn_s_barrier();

        // ---- phase 1: mi 2-3, stage B1(t+2) ----
        bf16x8 af2[2][2];
#pragma unroll
        for (int mi = 0; mi < 2; ++mi)
#pragma unroll
            for (int kk = 0; kk < 2; ++kk)
                af2[mi][kk] = lds_frag(sAc, wm * 64 + (2 + mi) * 16 + lr, kk, lg);
        if (t + 2 < nt)
            stage_unit(Bg + (size_t)128 * K + kb2, K, sB + nb * 16384 + 8192, tid);

        __builtin_amdgcn_s_setprio(1);
#pragma unroll
        for (int kk = 0; kk < 2; ++kk)
#pragma unroll
            for (int mi = 0; mi < 2; ++mi)
#pragma unroll
                for (int n = 0; n < 4; ++n)
                    acc[2 + mi][n] = __builtin_amdgcn_mfma_f32_16x16x32_bf16(
                        af2[mi][kk], bfr[n][kk], acc[2 + mi][n], 0, 0, 0);
        __builtin_amdgcn_s_setprio(0);
        __builtin_amdgcn_s_barrier();
    }

    // epilogue
#pragma unroll
    for (int n = 0; n < 4; ++n) {
        int col = colBase + wn * 64 + n * 16 + lr;
        float bv = HB ? bias[col] : 0.f;
#pragma unroll
        for (int m = 0; m < 4; ++m) {
            int row0 = rowBase + wm * 64 + m * 16 + lg * 4;
#pragma unroll
            for (int i = 0; i < 4; ++i) {
                float v = acc[m][n][i] + bv;
                if (RELU) v = v > 0.f ? v : 0.f;
                C[(size_t)(row0 + i) * N + col] = f2b(v);
            }
        }
    }
}

// ---------- groupedA (512 thr, 1832 blocks) ----------
// [0,256)      GEMM1: h1 = relu(featB @ W1T^T + b1)  M=4096 N=2048 K=1024
// [256,288)    W34 = W3c @ WhT^T                     M=2048 N=512  K=1024
// [288,296)    c[n] = b34 . w[:,n]
// [296,1320)   W2 [2048,2048] -> W2T (1024 64x64 tiles)
// [1320,1832)  w  [512,4096]  -> wTb (512 tiles)
__global__ __launch_bounds__(512, 1) void groupedA_kernel(
    const u16* __restrict__ featB, const u16* __restrict__ W1T,
    const float* __restrict__ b1, u16* __restrict__ h1,
    const u16* __restrict__ W3c, const u16* __restrict__ WhT, u16* __restrict__ W34,
    const float* __restrict__ b34, const float* __restrict__ w, float* __restrict__ c,
    const float* __restrict__ W2, u16* __restrict__ W2T,
    u16* __restrict__ wTb) {
    __shared__ __align__(16) u16 sA[3 * 8192];
    __shared__ __align__(16) u16 sB[3 * 16384];
    const int b = blockIdx.x, tid = threadIdx.x;
    if (b < 256) {
        gemm8_body<1, 1>(featB, W1T, b1, h1, 2048, 1024, b & 7, b >> 3, sA, sB);
    } else if (b < 288) {
        int g = b - 256;
        gemm8_body<0, 0>(W3c, WhT, nullptr, W34, 512, 1024, g & 1, g >> 1, sA, sB);
    } else if (b < 296) {
        int n = (b - 288) * 512 + tid;  // [0,4096)
        float s = 0.f;
        for (int j = 0; j < 512; ++j)
            s += b34[j] * w[(size_t)j * 4096 + n];
        c[n] = s;
    } else if (b < 1320) {
        transpose64_512(W2, W2T, 2048, 2048, b - 296, tid, (float(*)[65])sA);
    } else {
        transpose64_512(w, wTb, 512, 4096, b - 1320, tid, (float(*)[65])sA);
    }
}

// ---------- groupedB (512 thr, 512 blocks) ----------
// [0,256)    GEMM2: h2 = relu(h1 @ W2T^T + b2)  M=4096 N=2048 K=2048
// [256,512)  UT = wTb @ W34^T                   M=4096 N=2048 K=512
__global__ __launch_bounds__(512, 1) void groupedB_kernel(
    const u16* __restrict__ h1, const u16* __restrict__ W2T,
    const float* __restrict__ b2, u16* __restrict__ h2,
    const u16* __restrict__ wTb, const u16* __restrict__ W34, u16* __restrict__ UT) {
    __shared__ __align__(16) u16 sA[3 * 8192];
    __shared__ __align__(16) u16 sB[3 * 16384];
    const int b = blockIdx.x;
    if (b < 256) {
        gemm8_body<1, 1>(h1, W2T, b2, h2, 2048, 2048, b & 7, b >> 3, sA, sB);
    } else {
        int g = b - 256;
        gemm8_body<0, 0>(wTb, W34, nullptr, UT, 2048, 512, g & 7, g >> 3, sA, sB);
    }
}

// ---------- final dot: out[n] = c[n] + sum_k h2[n,k]*UT[n,k] ----------
__global__ __launch_bounds__(256) void dot_kernel(
    const u16* __restrict__ h2, const u16* __restrict__ UT,
    const float* __restrict__ c, float* __restrict__ out) {
    const int n = blockIdx.x * 4 + (threadIdx.x >> 6);
    const int lane = threadIdx.x & 63;
    const u16* hrow = h2 + (size_t)n * 2048;
    const u16* urow = UT + (size_t)n * 2048;
    float s = 0.f;
#pragma unroll
    for (int chk = 0; chk < 4; ++chk) {
        int o = chk * 512 + lane * 8;
        u16x8 hv = *(const u16x8*)(hrow + o);
        u16x8 uv = *(const u16x8*)(urow + o);
#pragma unroll
        for (int t = 0; t < 8; ++t) s += b2f(hv[t]) * b2f(uv[t]);
    }
#pragma unroll
    for (int off = 32; off; off >>= 1) s += __shfl_xor(s, off);
    if (lane == 0) out[n] = c[n] + s;
}

// ---------- launch ----------
extern "C" void kernel_launch(void* const* d_in, const int* in_sizes, int n_in,
                              void* d_out, int out_size, void* d_ws, size_t ws_size,
                              hipStream_t stream) {
    const float* features = (const float*)d_in[0];
    const float* W1 = (const float*)d_in[1];
    const float* b1 = (const float*)d_in[2];
    const float* W2 = (const float*)d_in[3];
    const float* b2 = (const float*)d_in[4];
    const float* W3 = (const float*)d_in[5];
    const float* b3 = (const float*)d_in[6];
    const float* Wh = (const float*)d_in[7];
    const float* bh = (const float*)d_in[8];
    const float* w  = (const float*)d_in[9];
    float* out = (float*)d_out;

    size_t off = 0;
    auto alloc = [&](size_t bytes) {
        void* p = (char*)d_ws + off;
        off += (bytes + 255) & ~(size_t)255;
        return p;
    };
    // featB/W1T/W3c dead after groupedA; UT (16MB) aliases them.
    u16* featB = (u16*)alloc((size_t)4096 * 1024 * 2);   // 8MB
    u16* W1T   = (u16*)alloc((size_t)2048 * 1024 * 2);   // 4MB
    u16* W3c   = (u16*)alloc((size_t)2048 * 1024 * 2);   // 4MB
    u16* UT    = featB;                                  // [4096,2048] bf16
    u16* WhT   = (u16*)alloc((size_t)512 * 1024 * 2);    // 1MB
    u16* W2T   = (u16*)alloc((size_t)2048 * 2048 * 2);   // 8MB
    u16* wTb   = (u16*)alloc((size_t)4096 * 512 * 2);    // 4MB
    u16* W34   = (u16*)alloc((size_t)2048 * 512 * 2);    // 2MB
    float* b34 = (float*)alloc((size_t)512 * 4);
    float* c   = (float*)alloc((size_t)4096 * 4);
    u16* h1    = (u16*)alloc((size_t)4096 * 2048 * 2);   // 16MB
    u16* h2    = (u16*)alloc((size_t)4096 * 2048 * 2);   // 16MB

    // 1. prep: feat/W3 cvt, W1T/WhT transposes, b34
    prep1_kernel<<<3714, 256, 0, stream>>>(features, featB, W1, W1T,
                                           W3, W3c, Wh, WhT, b3, bh, b34);

    // 2. groupedA: GEMM1 || W34 || c || W2T/wTb transposes (backfill)
    groupedA_kernel<<<1832, 512, 0, stream>>>(featB, W1T, b1, h1,
                                              W3c, WhT, W34, b34, w, c,
                                              W2, W2T, wTb);

    // 3. groupedB: GEMM2 || UT
    groupedB_kernel<<<512, 512, 0, stream>>>(h1, W2T, b2, h2, wTb, W34, UT);

    // 4. final row-dot
    dot_kernel<<<1024, 256, 0, stream>>>(h2, UT, c, out);
}

// Round 7
// 139.571 us; speedup vs baseline: 1.1367x; 1.0996x over previous
//
#include <hip/hip_runtime.h>
#include <cstdint>
#include <cstddef>

typedef unsigned short u16;
typedef __attribute__((ext_vector_type(8))) short bf16x8;
typedef __attribute__((ext_vector_type(8))) unsigned short u16x8;
typedef __attribute__((ext_vector_type(4))) unsigned short u16x4;
typedef __attribute__((ext_vector_type(4))) float f32x4;

// ---------- helpers ----------
__device__ __forceinline__ u16 f2b(float f) {
    union { float f; uint32_t u; } v; v.f = f;
    uint32_t u = v.u;
    uint32_t r = (u + 0x7FFFu + ((u >> 16) & 1u)) >> 16;
    return (u16)r;
}
__device__ __forceinline__ float b2f(u16 b) {
    union { uint32_t u; float f; } v; v.u = ((uint32_t)b) << 16;
    return v.f;
}
__device__ __forceinline__ void gload_lds16(const void* g, void* l) {
    __builtin_amdgcn_global_load_lds(
        (const __attribute__((address_space(1))) void*)g,
        (__attribute__((address_space(3))) void*)l,
        16, 0, 0);
}

// ---------- prep building blocks ----------
__device__ __forceinline__ void cvt_block(const float* __restrict__ in,
                                          u16* __restrict__ outp, int bb, int tid) {
    size_t base = (size_t)bb * 2048 + (size_t)tid * 8;
    const float4* p = (const float4*)(in + base);
    float4 a = p[0], c = p[1];
    u16x8 o;
    o[0] = f2b(a.x); o[1] = f2b(a.y); o[2] = f2b(a.z); o[3] = f2b(a.w);
    o[4] = f2b(c.x); o[5] = f2b(c.y); o[6] = f2b(c.z); o[7] = f2b(c.w);
    *(u16x8*)(outp + base) = o;
}

__device__ __forceinline__ void transpose64_256(const float* __restrict__ in,
                                                u16* __restrict__ outp,
                                                int K, int N, int t, int tid,
                                                float (*tile)[65]) {
    const int ntx = N >> 6;
    const int n0 = (t % ntx) * 64, k0 = (t / ntx) * 64;
    const int r0 = tid >> 4, c4 = tid & 15;
#pragma unroll
    for (int j = 0; j < 4; ++j) {
        int r = r0 + j * 16;
        float4 v = *(const float4*)(in + (size_t)(k0 + r) * N + n0 + c4 * 4);
        tile[r][c4 * 4 + 0] = v.x; tile[r][c4 * 4 + 1] = v.y;
        tile[r][c4 * 4 + 2] = v.z; tile[r][c4 * 4 + 3] = v.w;
    }
    __syncthreads();
    const int rr = tid >> 2;
#pragma unroll
    for (int j = 0; j < 4; ++j) {
        int ch = (tid & 3) + j * 4;
        u16x4 o;
        o[0] = f2b(tile[ch * 4 + 0][rr]); o[1] = f2b(tile[ch * 4 + 1][rr]);
        o[2] = f2b(tile[ch * 4 + 2][rr]); o[3] = f2b(tile[ch * 4 + 3][rr]);
        *(u16x4*)(outp + (size_t)(n0 + rr) * K + k0 + ch * 4) = o;
    }
    __syncthreads();
}

__device__ __forceinline__ void transpose64_512(const float* __restrict__ in,
                                                u16* __restrict__ outp,
                                                int K, int N, int t, int tid,
                                                float (*tile)[65]) {
    const int ntx = N >> 6;
    const int n0 = (t % ntx) * 64, k0 = (t / ntx) * 64;
    const int r0 = tid >> 4, c4 = tid & 15;
#pragma unroll
    for (int j = 0; j < 2; ++j) {
        int r = r0 + j * 32;
        float4 v = *(const float4*)(in + (size_t)(k0 + r) * N + n0 + c4 * 4);
        tile[r][c4 * 4 + 0] = v.x; tile[r][c4 * 4 + 1] = v.y;
        tile[r][c4 * 4 + 2] = v.z; tile[r][c4 * 4 + 3] = v.w;
    }
    __syncthreads();
    const int rr = tid >> 3;
#pragma unroll
    for (int j = 0; j < 2; ++j) {
        int ch = (tid & 7) + j * 8;
        u16x4 o;
        o[0] = f2b(tile[ch * 4 + 0][rr]); o[1] = f2b(tile[ch * 4 + 1][rr]);
        o[2] = f2b(tile[ch * 4 + 2][rr]); o[3] = f2b(tile[ch * 4 + 3][rr]);
        *(u16x4*)(outp + (size_t)(n0 + rr) * K + k0 + ch * 4) = o;
    }
    __syncthreads();
}

// ---------- prep1 (256 thr, 3714 blocks) ----------
__global__ __launch_bounds__(256) void prep1_kernel(
    const float* __restrict__ feat, u16* __restrict__ featB,
    const float* __restrict__ W1, u16* __restrict__ W1T,
    const float* __restrict__ W3, u16* __restrict__ W3c,
    const float* __restrict__ Wh, u16* __restrict__ WhT,
    const float* __restrict__ b3, const float* __restrict__ bh,
    float* __restrict__ b34) {
    __shared__ float tile[64][65];
    const int b = blockIdx.x, tid = threadIdx.x;
    if (b < 2048) { cvt_block(feat, featB, b, tid); return; }
    if (b < 3072) { cvt_block(W3, W3c, b - 2048, tid); return; }
    if (b < 3584) { transpose64_256(W1, W1T, 1024, 2048, b - 3072, tid, tile); return; }
    if (b < 3712) { transpose64_256(Wh, WhT, 1024, 512, b - 3584, tid, tile); return; }
    {
        int j = (b - 3712) * 256 + tid;  // [0,512)
        float s = bh[j];
        for (int k = 0; k < 1024; ++k)
            s += b3[k] * Wh[(size_t)k * 512 + j];
        b34[j] = s;
    }
}

// =====================================================================
// 256x256 4-phase pipelined GEMM (m201-geometry port).
// BK=64, 512 threads = 8 waves (2m x 4n), per-wave 128x64, acc[8][4].
// LDS: 2 dbuf x (A 32KB + B 32KB) = 128KB, organized as 4 quanta of
// 64 rows x 64 cols (8KB) per operand per buffer.
// Per phase: {ds_read subtile; stage 2 quanta of tile t+1; barrier;
// lgkmcnt(0); setprio(1); 16 MFMA; setprio(0); barrier}.
// Counted gates: vmcnt(4) at p1, vmcnt(2) at p3 (never 0 mid-loop).
// XOR swizzle ch=(c&7)^(r&7) on staging source; same XOR on ds_read.
// =====================================================================

// stage one 8KB quantum (64 rows x 64 bf16): 1 load/thread, source
// chunk pre-swizzled so linear LDS dest + swizzled read agree.
__device__ __forceinline__ void stage_q(const u16* __restrict__ g, int ldg,
                                        u16* lds, int tid) {
    int r = tid >> 3;
    int ch = (tid & 7) ^ (r & 7);
    gload_lds16(g + (size_t)r * ldg + ch * 8, (char*)lds + tid * 16);
}

// read one MFMA fragment from a swizzled 8KB quantum
__device__ __forceinline__ bf16x8 lds_frag(const u16* s, int row, int kk, int lg) {
    int byte = (row << 7) + (kk << 6) + (lg << 4);
    byte ^= (row & 7) << 4;
    return *(const bf16x8*)((const char*)s + byte);
}

#define CLUSTER16(MB, NB, AARR, BARR)                                          \
    do {                                                                       \
        __builtin_amdgcn_s_setprio(1);                                         \
        _Pragma("unroll") for (int kk = 0; kk < 2; ++kk)                       \
            _Pragma("unroll") for (int m = 0; m < 4; ++m)                      \
                _Pragma("unroll") for (int n = 0; n < 2; ++n)                  \
                    acc[(MB) + m][(NB) + n] =                                  \
                        __builtin_amdgcn_mfma_f32_16x16x32_bf16(               \
                            AARR[m][kk], BARR[n][kk],                          \
                            acc[(MB) + m][(NB) + n], 0, 0, 0);                 \
        __builtin_amdgcn_s_setprio(0);                                         \
    } while (0)

template <int RELU, int HB>
__device__ __forceinline__ void gemm256_body(
    const u16* __restrict__ A, const u16* __restrict__ BT,
    const float* __restrict__ bias, u16* __restrict__ C,
    int N, int K, int bx, int by, u16* sA, u16* sB) {
    const int tid = threadIdx.x;
    const int lane = tid & 63;
    const int wv = tid >> 6;
    const int wm = wv >> 2, wn = wv & 3;   // 2 x 4 waves, per-wave 128x64
    const int lr = lane & 15, lg = lane >> 4;
    const int rowBase = by * 256, colBase = bx * 256;
    const int nt = K >> 6;

    const u16* Ag = A + (size_t)rowBase * K;
    const u16* Bg = BT + (size_t)colBase * K;

    f32x4 acc[8][4] = {};

    // prologue: stage tile 0 fully (8 quanta), drain, barrier
#pragma unroll
    for (int q = 0; q < 4; ++q) stage_q(Ag + (size_t)(q * 64) * K, K, sA + q * 4096, tid);
#pragma unroll
    for (int q = 0; q < 4; ++q) stage_q(Bg + (size_t)(q * 64) * K, K, sB + q * 4096, tid);
    asm volatile("s_waitcnt vmcnt(0)" ::: "memory");
    __builtin_amdgcn_sched_barrier(0);
    __builtin_amdgcn_s_barrier();

    for (int t = 0; t < nt; ++t) {
        const int cur = t & 1, nxt = cur ^ 1;
        const u16* sAc = sA + cur * 16384;
        const u16* sBc = sB + cur * 16384;
        u16* sAn = sA + nxt * 16384;
        u16* sBn = sB + nxt * 16384;
        const int kb = (t + 1) << 6;
        const bool more = (t + 1 < nt);

        bf16x8 bA[4][2], bB0[2][2], bB1[2][2];

        // ---- phase 0: ds_read A-mh0(8) + B-nh0(4); stage B-q0,B-q1 ----
#pragma unroll
        for (int m = 0; m < 4; ++m)
#pragma unroll
            for (int kk = 0; kk < 2; ++kk)
                bA[m][kk] = lds_frag(sAc + wm * 8192, m * 16 + lr, kk, lg);
#pragma unroll
        for (int n = 0; n < 2; ++n)
#pragma unroll
            for (int kk = 0; kk < 2; ++kk)
                bB0[n][kk] = lds_frag(sBc + wn * 4096, n * 16 + lr, kk, lg);
        if (more) {
            stage_q(Bg + kb, K, sBn, tid);
            stage_q(Bg + (size_t)64 * K + kb, K, sBn + 4096, tid);
        }
        __builtin_amdgcn_s_barrier();
        asm volatile("s_waitcnt lgkmcnt(0)" ::: "memory");
        __builtin_amdgcn_sched_barrier(0);
        CLUSTER16(0, 0, bA, bB0);
        __builtin_amdgcn_s_barrier();

        // ---- phase 1: ds_read B-nh1(4); stage B-q2,B-q3; vmcnt(4) ----
#pragma unroll
        for (int n = 0; n < 2; ++n)
#pragma unroll
            for (int kk = 0; kk < 2; ++kk)
                bB1[n][kk] = lds_frag(sBc + wn * 4096, (2 + n) * 16 + lr, kk, lg);
        if (more) {
            stage_q(Bg + (size_t)128 * K + kb, K, sBn + 8192, tid);
            stage_q(Bg + (size_t)192 * K + kb, K, sBn + 12288, tid);
            asm volatile("s_waitcnt vmcnt(4)" ::: "memory");
        } else {
            asm volatile("s_waitcnt vmcnt(0)" ::: "memory");
        }
        __builtin_amdgcn_sched_barrier(0);
        __builtin_amdgcn_s_barrier();
        asm volatile("s_waitcnt lgkmcnt(0)" ::: "memory");
        __builtin_amdgcn_sched_barrier(0);
        CLUSTER16(0, 2, bA, bB1);
        __builtin_amdgcn_s_barrier();

        // ---- phase 2: ds_read A-mh1(8); stage A-q0,A-q2 ----
#pragma unroll
        for (int m = 0; m < 4; ++m)
#pragma unroll
            for (int kk = 0; kk < 2; ++kk)
                bA[m][kk] = lds_frag(sAc + wm * 8192 + 4096, m * 16 + lr, kk, lg);
        if (more) {
            stage_q(Ag + kb, K, sAn, tid);
            stage_q(Ag + (size_t)128 * K + kb, K, sAn + 8192, tid);
        }
        __builtin_amdgcn_s_barrier();
        asm volatile("s_waitcnt lgkmcnt(0)" ::: "memory");
        __builtin_amdgcn_sched_barrier(0);
        CLUSTER16(4, 0, bA, bB0);
        __builtin_amdgcn_s_barrier();

        // ---- phase 3: stage A-q1,A-q3; vmcnt(2) ----
        if (more) {
            stage_q(Ag + (size_t)64 * K + kb, K, sAn + 4096, tid);
            stage_q(Ag + (size_t)192 * K + kb, K, sAn + 12288, tid);
            asm volatile("s_waitcnt vmcnt(2)" ::: "memory");
        }
        __builtin_amdgcn_sched_barrier(0);
        __builtin_amdgcn_s_barrier();
        CLUSTER16(4, 2, bA, bB1);
        __builtin_amdgcn_s_barrier();
    }

    // epilogue: bias (+relu), store bf16
#pragma unroll
    for (int n = 0; n < 4; ++n) {
        int col = colBase + wn * 64 + n * 16 + lr;
        float bv = HB ? bias[col] : 0.f;
#pragma unroll
        for (int m = 0; m < 8; ++m) {
            int row0 = rowBase + wm * 128 + m * 16 + lg * 4;
#pragma unroll
            for (int i = 0; i < 4; ++i) {
                float v = acc[m][n][i] + bv;
                if (RELU) v = v > 0.f ? v : 0.f;
                C[(size_t)(row0 + i) * N + col] = f2b(v);
            }
        }
    }
}

// ---------- groupedA (512 thr, 1688 blocks) ----------
// [0,128)      GEMM1: h1 = relu(featB @ W1T^T + b1)  M=4096 N=2048 K=1024
// [128,144)    W34 = W3c @ WhT^T                     M=2048 N=512  K=1024
// [144,152)    c[n] = b34 . w[:,n]
// [152,1176)   W2 [2048,2048] -> W2T (1024 64x64 tiles)
// [1176,1688)  w  [512,4096]  -> wTb (512 tiles)
__global__ __launch_bounds__(512, 2) void groupedA_kernel(
    const u16* __restrict__ featB, const u16* __restrict__ W1T,
    const float* __restrict__ b1, u16* __restrict__ h1,
    const u16* __restrict__ W3c, const u16* __restrict__ WhT, u16* __restrict__ W34,
    const float* __restrict__ b34, const float* __restrict__ w, float* __restrict__ c,
    const float* __restrict__ W2, u16* __restrict__ W2T,
    u16* __restrict__ wTb) {
    __shared__ __align__(16) u16 sA[2 * 16384];
    __shared__ __align__(16) u16 sB[2 * 16384];
    const int b = blockIdx.x, tid = threadIdx.x;
    if (b < 128) {
        gemm256_body<1, 1>(featB, W1T, b1, h1, 2048, 1024, b & 7, b >> 3, sA, sB);
    } else if (b < 144) {
        int g = b - 128;
        gemm256_body<0, 0>(W3c, WhT, nullptr, W34, 512, 1024, g & 1, g >> 1, sA, sB);
    } else if (b < 152) {
        int n = (b - 144) * 512 + tid;  // [0,4096)
        float s = 0.f;
        for (int j = 0; j < 512; ++j)
            s += b34[j] * w[(size_t)j * 4096 + n];
        c[n] = s;
    } else if (b < 1176) {
        transpose64_512(W2, W2T, 2048, 2048, b - 152, tid, (float(*)[65])sA);
    } else {
        transpose64_512(w, wTb, 512, 4096, b - 1176, tid, (float(*)[65])sA);
    }
}

// ---------- groupedB (512 thr, 256 blocks = 1/CU) ----------
// [0,128)    GEMM2: h2 = relu(h1 @ W2T^T + b2)  M=4096 N=2048 K=2048
// [128,256)  UT = wTb @ W34^T                   M=4096 N=2048 K=512
__global__ __launch_bounds__(512, 2) void groupedB_kernel(
    const u16* __restrict__ h1, const u16* __restrict__ W2T,
    const float* __restrict__ b2, u16* __restrict__ h2,
    const u16* __restrict__ wTb, const u16* __restrict__ W34, u16* __restrict__ UT) {
    __shared__ __align__(16) u16 sA[2 * 16384];
    __shared__ __align__(16) u16 sB[2 * 16384];
    const int b = blockIdx.x;
    if (b < 128) {
        gemm256_body<1, 1>(h1, W2T, b2, h2, 2048, 2048, b & 7, b >> 3, sA, sB);
    } else {
        int g = b - 128;
        gemm256_body<0, 0>(wTb, W34, nullptr, UT, 2048, 512, g & 7, g >> 3, sA, sB);
    }
}

// ---------- final dot: out[n] = c[n] + sum_k h2[n,k]*UT[n,k] ----------
__global__ __launch_bounds__(256) void dot_kernel(
    const u16* __restrict__ h2, const u16* __restrict__ UT,
    const float* __restrict__ c, float* __restrict__ out) {
    const int n = blockIdx.x * 4 + (threadIdx.x >> 6);
    const int lane = threadIdx.x & 63;
    const u16* hrow = h2 + (size_t)n * 2048;
    const u16* urow = UT + (size_t)n * 2048;
    float s = 0.f;
#pragma unroll
    for (int chk = 0; chk < 4; ++chk) {
        int o = chk * 512 + lane * 8;
        u16x8 hv = *(const u16x8*)(hrow + o);
        u16x8 uv = *(const u16x8*)(urow + o);
#pragma unroll
        for (int t = 0; t < 8; ++t) s += b2f(hv[t]) * b2f(uv[t]);
    }
#pragma unroll
    for (int off = 32; off; off >>= 1) s += __shfl_xor(s, off);
    if (lane == 0) out[n] = c[n] + s;
}

// ---------- launch ----------
extern "C" void kernel_launch(void* const* d_in, const int* in_sizes, int n_in,
                              void* d_out, int out_size, void* d_ws, size_t ws_size,
                              hipStream_t stream) {
    const float* features = (const float*)d_in[0];
    const float* W1 = (const float*)d_in[1];
    const float* b1 = (const float*)d_in[2];
    const float* W2 = (const float*)d_in[3];
    const float* b2 = (const float*)d_in[4];
    const float* W3 = (const float*)d_in[5];
    const float* b3 = (const float*)d_in[6];
    const float* Wh = (const float*)d_in[7];
    const float* bh = (const float*)d_in[8];
    const float* w  = (const float*)d_in[9];
    float* out = (float*)d_out;

    size_t off = 0;
    auto alloc = [&](size_t bytes) {
        void* p = (char*)d_ws + off;
        off += (bytes + 255) & ~(size_t)255;
        return p;
    };
    // featB/W1T/W3c dead after groupedA; UT (16MB) aliases them.
    u16* featB = (u16*)alloc((size_t)4096 * 1024 * 2);   // 8MB
    u16* W1T   = (u16*)alloc((size_t)2048 * 1024 * 2);   // 4MB
    u16* W3c   = (u16*)alloc((size_t)2048 * 1024 * 2);   // 4MB
    u16* UT    = featB;                                  // [4096,2048] bf16
    u16* WhT   = (u16*)alloc((size_t)512 * 1024 * 2);    // 1MB
    u16* W2T   = (u16*)alloc((size_t)2048 * 2048 * 2);   // 8MB
    u16* wTb   = (u16*)alloc((size_t)4096 * 512 * 2);    // 4MB
    u16* W34   = (u16*)alloc((size_t)2048 * 512 * 2);    // 2MB
    float* b34 = (float*)alloc((size_t)512 * 4);
    float* c   = (float*)alloc((size_t)4096 * 4);
    u16* h1    = (u16*)alloc((size_t)4096 * 2048 * 2);   // 16MB
    u16* h2    = (u16*)alloc((size_t)4096 * 2048 * 2);   // 16MB

    // 1. prep: feat/W3 cvt, W1T/WhT transposes, b34
    prep1_kernel<<<3714, 256, 0, stream>>>(features, featB, W1, W1T,
                                           W3, W3c, Wh, WhT, b3, bh, b34);

    // 2. groupedA: GEMM1 || W34 || c || W2T/wTb transposes (backfill)
    groupedA_kernel<<<1688, 512, 0, stream>>>(featB, W1T, b1, h1,
                                              W3c, WhT, W34, b34, w, c,
                                              W2, W2T, wTb);

    // 3. groupedB: GEMM2 || UT
    groupedB_kernel<<<256, 512, 0, stream>>>(h1, W2T, b2, h2, wTb, W34, UT);

    // 4. final row-dot
    dot_kernel<<<1024, 256, 0, stream>>>(h2, UT, c, out);
}

// Round 8
// 127.959 us; speedup vs baseline: 1.2398x; 1.0908x over previous
//
#include <hip/hip_runtime.h>
#include <cstdint>
#include <cstddef>

typedef unsigned short u16;
typedef __attribute__((ext_vector_type(8))) short bf16x8;
typedef __attribute__((ext_vector_type(8))) unsigned short u16x8;
typedef __attribute__((ext_vector_type(4))) unsigned short u16x4;
typedef __attribute__((ext_vector_type(4))) float f32x4;

// ---------- helpers ----------
__device__ __forceinline__ u16 f2b(float f) {
    union { float f; uint32_t u; } v; v.f = f;
    uint32_t u = v.u;
    uint32_t r = (u + 0x7FFFu + ((u >> 16) & 1u)) >> 16;
    return (u16)r;
}
__device__ __forceinline__ float b2f(u16 b) {
    union { uint32_t u; float f; } v; v.u = ((uint32_t)b) << 16;
    return v.f;
}
__device__ __forceinline__ void gload_lds16(const void* g, void* l) {
    __builtin_amdgcn_global_load_lds(
        (const __attribute__((address_space(1))) void*)g,
        (__attribute__((address_space(3))) void*)l,
        16, 0, 0);
}

// ---------- prep building blocks ----------
__device__ __forceinline__ void cvt_block(const float* __restrict__ in,
                                          u16* __restrict__ outp, int bb, int tid) {
    size_t base = (size_t)bb * 2048 + (size_t)tid * 8;
    const float4* p = (const float4*)(in + base);
    float4 a = p[0], c = p[1];
    u16x8 o;
    o[0] = f2b(a.x); o[1] = f2b(a.y); o[2] = f2b(a.z); o[3] = f2b(a.w);
    o[4] = f2b(c.x); o[5] = f2b(c.y); o[6] = f2b(c.z); o[7] = f2b(c.w);
    *(u16x8*)(outp + base) = o;
}

__device__ __forceinline__ void transpose64_256(const float* __restrict__ in,
                                                u16* __restrict__ outp,
                                                int K, int N, int t, int tid,
                                                float (*tile)[65]) {
    const int ntx = N >> 6;
    const int n0 = (t % ntx) * 64, k0 = (t / ntx) * 64;
    const int r0 = tid >> 4, c4 = tid & 15;
#pragma unroll
    for (int j = 0; j < 4; ++j) {
        int r = r0 + j * 16;
        float4 v = *(const float4*)(in + (size_t)(k0 + r) * N + n0 + c4 * 4);
        tile[r][c4 * 4 + 0] = v.x; tile[r][c4 * 4 + 1] = v.y;
        tile[r][c4 * 4 + 2] = v.z; tile[r][c4 * 4 + 3] = v.w;
    }
    __syncthreads();
    const int rr = tid >> 2;
#pragma unroll
    for (int j = 0; j < 4; ++j) {
        int ch = (tid & 3) + j * 4;
        u16x4 o;
        o[0] = f2b(tile[ch * 4 + 0][rr]); o[1] = f2b(tile[ch * 4 + 1][rr]);
        o[2] = f2b(tile[ch * 4 + 2][rr]); o[3] = f2b(tile[ch * 4 + 3][rr]);
        *(u16x4*)(outp + (size_t)(n0 + rr) * K + k0 + ch * 4) = o;
    }
    __syncthreads();
}

__device__ __forceinline__ void transpose64_512(const float* __restrict__ in,
                                                u16* __restrict__ outp,
                                                int K, int N, int t, int tid,
                                                float (*tile)[65]) {
    const int ntx = N >> 6;
    const int n0 = (t % ntx) * 64, k0 = (t / ntx) * 64;
    const int r0 = tid >> 4, c4 = tid & 15;
#pragma unroll
    for (int j = 0; j < 2; ++j) {
        int r = r0 + j * 32;
        float4 v = *(const float4*)(in + (size_t)(k0 + r) * N + n0 + c4 * 4);
        tile[r][c4 * 4 + 0] = v.x; tile[r][c4 * 4 + 1] = v.y;
        tile[r][c4 * 4 + 2] = v.z; tile[r][c4 * 4 + 3] = v.w;
    }
    __syncthreads();
    const int rr = tid >> 3;
#pragma unroll
    for (int j = 0; j < 2; ++j) {
        int ch = (tid & 7) + j * 8;
        u16x4 o;
        o[0] = f2b(tile[ch * 4 + 0][rr]); o[1] = f2b(tile[ch * 4 + 1][rr]);
        o[2] = f2b(tile[ch * 4 + 2][rr]); o[3] = f2b(tile[ch * 4 + 3][rr]);
        *(u16x4*)(outp + (size_t)(n0 + rr) * K + k0 + ch * 4) = o;
    }
    __syncthreads();
}

// ---------- prep1 (256 thr, 4226 blocks) ----------
// [0,2048)     feat [4096,1024] f32->bf16
// [2048,3072)  W3   [2048,1024] f32->bf16
// [3072,3584)  W1   [1024,2048] -> W1T [2048,1024]
// [3584,3712)  Wh   [1024,512]  -> WhT [512,1024]
// [3712,4224)  w    [512,4096]  -> wTb [4096,512]
// [4224,4226)  b34[j] = b3 . Wh[:,j] + bh[j]
__global__ __launch_bounds__(256) void prep1_kernel(
    const float* __restrict__ feat, u16* __restrict__ featB,
    const float* __restrict__ W1, u16* __restrict__ W1T,
    const float* __restrict__ W3, u16* __restrict__ W3c,
    const float* __restrict__ Wh, u16* __restrict__ WhT,
    const float* __restrict__ w, u16* __restrict__ wTb,
    const float* __restrict__ b3, const float* __restrict__ bh,
    float* __restrict__ b34) {
    __shared__ float tile[64][65];
    const int b = blockIdx.x, tid = threadIdx.x;
    if (b < 2048) { cvt_block(feat, featB, b, tid); return; }
    if (b < 3072) { cvt_block(W3, W3c, b - 2048, tid); return; }
    if (b < 3584) { transpose64_256(W1, W1T, 1024, 2048, b - 3072, tid, tile); return; }
    if (b < 3712) { transpose64_256(Wh, WhT, 1024, 512, b - 3584, tid, tile); return; }
    if (b < 4224) { transpose64_256(w, wTb, 512, 4096, b - 3712, tid, tile); return; }
    {
        int j = (b - 4224) * 256 + tid;  // [0,512)
        float s = bh[j];
        for (int k = 0; k < 1024; ++k)
            s += b3[k] * Wh[(size_t)k * 512 + j];
        b34[j] = s;
    }
}

// =====================================================================
// 256x128-tile pipelined GEMM core. BK=64, 512 thr = 8 waves (4m x 2n),
// per-wave 64x64, acc[4][4]. LDS: 3 buffers x (A 32KB + B 16KB) = 144KB.
// 2 phases/K-tile (kk=0 / kk=1), 16 MFMA each; stage tile t+2 while
// computing t (3 loads/thread/phase); ONE counted gate vmcnt(6)/K-tile
// (2 tiles = 12 loads may stay in flight); 2 barriers/K-tile.
// XOR swizzle ch=(c&7)^(r&7) on staging source; same XOR on ds_read.
// =====================================================================

__device__ __forceinline__ void stage_q(const u16* __restrict__ g, int ldg,
                                        u16* lds, int tid) {
    int r = tid >> 3;
    int ch = (tid & 7) ^ (r & 7);
    gload_lds16(g + (size_t)r * ldg + ch * 8, (char*)lds + tid * 16);
}

__device__ __forceinline__ bf16x8 lds_frag(const u16* s, int row, int kk, int lg) {
    int byte = (row << 7) + (kk << 6) + (lg << 4);
    byte ^= (row & 7) << 4;
    return *(const bf16x8*)((const char*)s + byte);
}

#define MFMA_CLUSTER(AF, BF)                                                   \
    do {                                                                       \
        __builtin_amdgcn_s_setprio(1);                                         \
        _Pragma("unroll") for (int m = 0; m < 4; ++m)                          \
            _Pragma("unroll") for (int n = 0; n < 4; ++n)                      \
                acc[m][n] = __builtin_amdgcn_mfma_f32_16x16x32_bf16(           \
                    AF[m], BF[n], acc[m][n], 0, 0, 0);                         \
        __builtin_amdgcn_s_setprio(0);                                         \
    } while (0)

// Ag/Bg pre-offset to the block's row/col panels; row stride = K.
__device__ __forceinline__ void gemm_loop(
    const u16* __restrict__ Ag, const u16* __restrict__ Bg, int K,
    u16* sA, u16* sB, f32x4 (&acc)[4][4],
    int tid, int wm, int wn, int lr, int lg) {
    const int nt = K >> 6;
    // prologue: stage tiles 0 and 1 (6 loads/thread each)
    stage_q(Ag, K, sA, tid);
    stage_q(Ag + (size_t)64 * K, K, sA + 4096, tid);
    stage_q(Ag + (size_t)128 * K, K, sA + 8192, tid);
    stage_q(Ag + (size_t)192 * K, K, sA + 12288, tid);
    stage_q(Bg, K, sB, tid);
    stage_q(Bg + (size_t)64 * K, K, sB + 4096, tid);
    stage_q(Ag + 64, K, sA + 16384, tid);
    stage_q(Ag + (size_t)64 * K + 64, K, sA + 16384 + 4096, tid);
    stage_q(Ag + (size_t)128 * K + 64, K, sA + 16384 + 8192, tid);
    stage_q(Ag + (size_t)192 * K + 64, K, sA + 16384 + 12288, tid);
    stage_q(Bg + 64, K, sB + 8192, tid);
    stage_q(Bg + (size_t)64 * K + 64, K, sB + 8192 + 4096, tid);
    asm volatile("s_waitcnt vmcnt(6)" ::: "memory");
    __builtin_amdgcn_sched_barrier(0);
    __builtin_amdgcn_s_barrier();

    for (int t = 0; t < nt; ++t) {
        const int cb = t % 3, nb = (t + 2) % 3;
        const u16* sAc = sA + cb * 16384;
        const u16* sBc = sB + cb * 8192;
        u16* sAn = sA + nb * 16384;
        u16* sBn = sB + nb * 8192;
        const int kb = (t + 2) << 6;
        const bool more2 = (t + 2) < nt;

        // ---- phase 0: kk=0 ----
        bf16x8 a0[4], b0[4];
#pragma unroll
        for (int m = 0; m < 4; ++m)
            a0[m] = lds_frag(sAc + wm * 4096, m * 16 + lr, 0, lg);
#pragma unroll
        for (int n = 0; n < 4; ++n)
            b0[n] = lds_frag(sBc + wn * 4096, n * 16 + lr, 0, lg);
        if (more2) {
            stage_q(Bg + kb, K, sBn, tid);
            stage_q(Bg + (size_t)64 * K + kb, K, sBn + 4096, tid);
            stage_q(Ag + kb, K, sAn, tid);
        }
        asm volatile("s_waitcnt lgkmcnt(0)" ::: "memory");
        __builtin_amdgcn_sched_barrier(0);
        MFMA_CLUSTER(a0, b0);
        __builtin_amdgcn_s_barrier();

        // ---- phase 1: kk=1; gate ----
        bf16x8 a1[4], b1[4];
#pragma unroll
        for (int m = 0; m < 4; ++m)
            a1[m] = lds_frag(sAc + wm * 4096, m * 16 + lr, 1, lg);
#pragma unroll
        for (int n = 0; n < 4; ++n)
            b1[n] = lds_frag(sBc + wn * 4096, n * 16 + lr, 1, lg);
        if (more2) {
            stage_q(Ag + (size_t)64 * K + kb, K, sAn + 4096, tid);
            stage_q(Ag + (size_t)128 * K + kb, K, sAn + 8192, tid);
            stage_q(Ag + (size_t)192 * K + kb, K, sAn + 12288, tid);
            asm volatile("s_waitcnt vmcnt(6)" ::: "memory");
        } else if (t + 1 < nt) {
            asm volatile("s_waitcnt vmcnt(0)" ::: "memory");
        }
        __builtin_amdgcn_sched_barrier(0);
        asm volatile("s_waitcnt lgkmcnt(0)" ::: "memory");
        __builtin_amdgcn_sched_barrier(0);
        MFMA_CLUSTER(a1, b1);
        __builtin_amdgcn_s_barrier();
    }
}

// plain GEMM + store epilogue
template <int RELU, int HB>
__device__ __forceinline__ void gemm_store(
    const u16* __restrict__ A, const u16* __restrict__ BT,
    const float* __restrict__ bias, u16* __restrict__ C,
    int N, int K, int bx, int by, u16* sA, u16* sB) {
    const int tid = threadIdx.x;
    const int lane = tid & 63;
    const int wv = tid >> 6;
    const int wm = wv >> 1, wn = wv & 1;
    const int lr = lane & 15, lg = lane >> 4;
    const int rowBase = by * 256, colBase = bx * 128;
    f32x4 acc[4][4] = {};
    gemm_loop(A + (size_t)rowBase * K, BT + (size_t)colBase * K, K,
              sA, sB, acc, tid, wm, wn, lr, lg);
#pragma unroll
    for (int n = 0; n < 4; ++n) {
        int col = colBase + wn * 64 + n * 16 + lr;
        float bv = HB ? bias[col] : 0.f;
#pragma unroll
        for (int m = 0; m < 4; ++m) {
            int row0 = rowBase + wm * 64 + m * 16 + lg * 4;
#pragma unroll
            for (int i = 0; i < 4; ++i) {
                float v = acc[m][n][i] + bv;
                if (RELU) v = v > 0.f ? v : 0.f;
                C[(size_t)(row0 + i) * N + col] = f2b(v);
            }
        }
    }
}

// ---------- K2: midA (512 thr, 1320 blocks) ----------
// [0,32)      W34 = W3c @ WhT^T   M=2048 N=512 K=1024  (by=b>>2, bx=b&3)
// [32,288)    GEMM1: h1 = relu(featB @ W1T^T + b1)  M=4096 N=2048 K=1024
// [288,296)   out[n] = c[n] = b34 . w[:,n]
// [296,1320)  W2 [2048,2048] -> W2T (1024 64x64 tiles)
__global__ __launch_bounds__(512, 2) void midA_kernel(
    const u16* __restrict__ W3c, const u16* __restrict__ WhT, u16* __restrict__ W34,
    const u16* __restrict__ featB, const u16* __restrict__ W1T,
    const float* __restrict__ b1, u16* __restrict__ h1,
    const float* __restrict__ b34, const float* __restrict__ w,
    float* __restrict__ out,
    const float* __restrict__ W2, u16* __restrict__ W2T) {
    __shared__ __align__(16) u16 sA[3 * 16384];
    __shared__ __align__(16) u16 sB[3 * 8192];
    const int b = blockIdx.x, tid = threadIdx.x;
    if (b < 32) {
        gemm_store<0, 0>(W3c, WhT, nullptr, W34, 512, 1024, b & 3, b >> 2, sA, sB);
    } else if (b < 288) {
        int g = b - 32;
        gemm_store<1, 1>(featB, W1T, b1, h1, 2048, 1024, g & 15, g >> 4, sA, sB);
    } else if (b < 296) {
        int n = (b - 288) * 512 + tid;  // [0,4096)
        float s = 0.f;
        for (int j = 0; j < 512; ++j)
            s += b34[j] * w[(size_t)j * 4096 + n];
        out[n] = s;
    } else {
        transpose64_512(W2, W2T, 2048, 2048, b - 296, tid, (float(*)[65])sA);
    }
}

// ---------- K3: fused UT + GEMM2 + row-dot (512 thr, 256 blocks) ----------
// Per block (by,bx): rows rowBase..+256 of the 4096-dim, cols colBase..+128
// of the 2048-dim.
//  phase A: acc = UT-subtile = wTb[rows] @ W34[cols]^T (K=512) -> pack bf16
//  phase B: acc = z2-subtile = h1[rows] @ W2T[cols]^T (K=2048)
//  epilogue: out[row] += sum_col relu(z2+b2[col]) * ut[row,col]
__global__ __launch_bounds__(512, 2) void gemm2dot_kernel(
    const u16* __restrict__ h1, const u16* __restrict__ W2T,
    const float* __restrict__ b2,
    const u16* __restrict__ wTb, const u16* __restrict__ W34,
    float* __restrict__ out) {
    __shared__ __align__(16) u16 sA[3 * 16384];
    __shared__ __align__(16) u16 sB[3 * 8192];
    const int tid = threadIdx.x;
    const int lane = tid & 63;
    const int wv = tid >> 6;
    const int wm = wv >> 1, wn = wv & 1;
    const int lr = lane & 15, lg = lane >> 4;
    const int by = blockIdx.x >> 4, bx = blockIdx.x & 15;
    const int rowBase = by * 256, colBase = bx * 128;

    f32x4 acc[4][4] = {};
    // phase A: UT sub-tile in registers
    gemm_loop(wTb + (size_t)rowBase * 512, W34 + (size_t)colBase * 512, 512,
              sA, sB, acc, tid, wm, wn, lr, lg);
    u16x4 ut16[4][4];
#pragma unroll
    for (int m = 0; m < 4; ++m)
#pragma unroll
        for (int n = 0; n < 4; ++n) {
#pragma unroll
            for (int i = 0; i < 4; ++i) ut16[m][n][i] = f2b(acc[m][n][i]);
            acc[m][n] = (f32x4){0.f, 0.f, 0.f, 0.f};
        }
    // phase B: GEMM2
    gemm_loop(h1 + (size_t)rowBase * 2048, W2T + (size_t)colBase * 2048, 2048,
              sA, sB, acc, tid, wm, wn, lr, lg);
    // epilogue: relu + dot with ut16, reduce over cols, atomicAdd rows
    float psum[4][4] = {};
#pragma unroll
    for (int n = 0; n < 4; ++n) {
        int col = colBase + wn * 64 + n * 16 + lr;
        float bv = b2[col];
#pragma unroll
        for (int m = 0; m < 4; ++m)
#pragma unroll
            for (int i = 0; i < 4; ++i) {
                float v = acc[m][n][i] + bv;
                v = v > 0.f ? v : 0.f;
                psum[m][i] += v * b2f(ut16[m][n][i]);
            }
    }
#pragma unroll
    for (int m = 0; m < 4; ++m)
#pragma unroll
        for (int i = 0; i < 4; ++i) {
#pragma unroll
            for (int mask = 1; mask < 16; mask <<= 1)
                psum[m][i] += __shfl_xor(psum[m][i], mask);
        }
    if (lr == 0) {
#pragma unroll
        for (int m = 0; m < 4; ++m) {
            int row0 = rowBase + wm * 64 + m * 16 + lg * 4;
#pragma unroll
            for (int i = 0; i < 4; ++i)
                atomicAdd(&out[row0 + i], psum[m][i]);
        }
    }
}

// ---------- launch ----------
extern "C" void kernel_launch(void* const* d_in, const int* in_sizes, int n_in,
                              void* d_out, int out_size, void* d_ws, size_t ws_size,
                              hipStream_t stream) {
    const float* features = (const float*)d_in[0];
    const float* W1 = (const float*)d_in[1];
    const float* b1 = (const float*)d_in[2];
    const float* W2 = (const float*)d_in[3];
    const float* b2 = (const float*)d_in[4];
    const float* W3 = (const float*)d_in[5];
    const float* b3 = (const float*)d_in[6];
    const float* Wh = (const float*)d_in[7];
    const float* bh = (const float*)d_in[8];
    const float* w  = (const float*)d_in[9];
    float* out = (float*)d_out;

    size_t off = 0;
    auto alloc = [&](size_t bytes) {
        void* p = (char*)d_ws + off;
        off += (bytes + 255) & ~(size_t)255;
        return p;
    };
    u16* featB = (u16*)alloc((size_t)4096 * 1024 * 2);   // 8MB
    u16* W3c   = (u16*)alloc((size_t)2048 * 1024 * 2);   // 4MB
    u16* W1T   = (u16*)alloc((size_t)2048 * 1024 * 2);   // 4MB
    u16* WhT   = (u16*)alloc((size_t)512 * 1024 * 2);    // 1MB
    u16* wTb   = (u16*)alloc((size_t)4096 * 512 * 2);    // 4MB
    u16* W2T   = (u16*)alloc((size_t)2048 * 2048 * 2);   // 8MB
    u16* W34   = (u16*)alloc((size_t)2048 * 512 * 2);    // 2MB
    float* b34 = (float*)alloc((size_t)512 * 4);
    u16* h1    = (u16*)alloc((size_t)4096 * 2048 * 2);   // 16MB

    // K1: prep
    prep1_kernel<<<4226, 256, 0, stream>>>(features, featB, W1, W1T,
                                           W3, W3c, Wh, WhT, w, wTb,
                                           b3, bh, b34);

    // K2: W34 || GEMM1 || c->out || W2T
    midA_kernel<<<1320, 512, 0, stream>>>(W3c, WhT, W34,
                                          featB, W1T, b1, h1,
                                          b34, w, out, W2, W2T);

    // K3: fused UT + GEMM2 + dot (atomicAdd into out)
    gemm2dot_kernel<<<256, 512, 0, stream>>>(h1, W2T, b2, wTb, W34, out);
}